// Round 5
// baseline (2299.558 us; speedup 1.0000x reference)
//
#include <hip/hip_runtime.h>

#define N_NODES 20000
#define N_EDGES 320000
#define CDIM    256
#define BE      1024
#define NBLK    313      // ceil(N_EDGES/BE)
#define NBN     20       // ceil(N_NODES/BE)
#define CHUNK   4096
#define NCHUNK  ((N_EDGES + CHUNK - 1) / CHUNK)   // 79

#define OFF_X   0
#define OFF_EI  (N_NODES*CDIM)                 // 5120000
#define OFF_CL  (OFF_EI + 2*N_EDGES)           // 5760000
#define OFF_B   (OFF_CL + N_NODES)             // 5780000
#define OFF_NC  (OFF_B + N_NODES)              // 5800000

// ---------- XLA CPU tanh: rational approximation, plain mul/add f32 ----------
__device__ __forceinline__ float xla_tanh(float x) {
  float ax = fabsf(x);
  float xc = fminf(fmaxf(x, -9.0f), 9.0f);
  float x2 = __fmul_rn(xc, xc);
  float p = -2.76076847742355e-16f;
  p = __fadd_rn(__fmul_rn(p, x2), 2.00018790482477e-13f);
  p = __fadd_rn(__fmul_rn(p, x2), -8.60467152213735e-11f);
  p = __fadd_rn(__fmul_rn(p, x2), 5.12229709037114e-08f);
  p = __fadd_rn(__fmul_rn(p, x2), 1.48572235717979e-05f);
  p = __fadd_rn(__fmul_rn(p, x2), 6.37261928875436e-04f);
  p = __fadd_rn(__fmul_rn(p, x2), 4.89352455891786e-03f);
  float num = __fmul_rn(xc, p);
  float q = 1.19825839466702e-06f;
  q = __fadd_rn(__fmul_rn(q, x2), 1.18534705686654e-04f);
  q = __fadd_rn(__fmul_rn(q, x2), 2.26843463243900e-03f);
  q = __fadd_rn(__fmul_rn(q, x2), 4.89352518554385e-03f);
  float r = num / q;   // correctly-rounded f32 divide
  return (ax < 0.0004f) ? x : r;
}

// ---------- K0: per-node partial dots, sequential-k mul+add chain ----------
__global__ void k_node_dots(const float* __restrict__ x, const float* __restrict__ w,
                            float* __restrict__ p1, float* __restrict__ p2) {
  __shared__ float sw[2*CDIM];
  for (int i = threadIdx.x; i < 2*CDIM; i += blockDim.x) sw[i] = w[i];
  __syncthreads();
  int n = blockIdx.x * blockDim.x + threadIdx.x;
  if (n >= N_NODES) return;
  const float* row = x + (size_t)n * CDIM;
  float a1 = 0.f, a2 = 0.f;
  for (int k = 0; k < CDIM; ++k) {
    float xv = row[k];
    a1 = __fadd_rn(a1, __fmul_rn(xv, sw[k]));
    a2 = __fadd_rn(a2, __fmul_rn(xv, sw[CDIM + k]));
  }
  p1[n] = a1; p2[n] = a2;
}

// ---------- K1: edge scores + sort keys ----------
__global__ void k_edge_scores(const int* __restrict__ ei, const float* __restrict__ p1,
                              const float* __restrict__ p2, const float* __restrict__ lb,
                              float* __restrict__ e, unsigned* __restrict__ keyA,
                              int* __restrict__ payA) {
  int i = blockIdx.x * blockDim.x + threadIdx.x;
  if (i >= N_EDGES) return;
  int s = ei[i], d = ei[N_EDGES + i];
  float z = __fadd_rn(__fadd_rn(p1[s], p2[d]), lb[0]);
  float ev = __fadd_rn(xla_tanh(z), 0.5f);
  e[i] = ev;
  unsigned u = __float_as_uint(ev);
  u = (u >> 31) ? ~u : (u | 0x80000000u);   // ascending-order bits of e
  keyA[i] = ~u;                              // ascending key == descending e; ties stable by idx
  payA[i] = i;
}

// ---------- radix sort (stable LSD, 4x8 bits) ----------
__global__ void k_radix_hist(const unsigned* __restrict__ key, int n, int shift,
                             unsigned* __restrict__ hist) {
  __shared__ unsigned h[256];
  int t = threadIdx.x;
  h[t] = 0;
  __syncthreads();
  int base = blockIdx.x * BE;
  for (int j = t; j < BE; j += 256) {
    int idx = base + j;
    if (idx < n) atomicAdd(&h[(key[idx] >> shift) & 255u], 1u);
  }
  __syncthreads();
  hist[t * NBLK + blockIdx.x] = h[t];
}

__global__ void k_radix_scan(unsigned* __restrict__ hist) {
  __shared__ unsigned sums[256];
  int t = threadIdx.x;
  unsigned rs = 0;
  for (int b = 0; b < NBLK; ++b) rs += hist[t * NBLK + b];
  sums[t] = rs;
  __syncthreads();
  for (int off = 1; off < 256; off <<= 1) {
    unsigned u2 = (t >= off) ? sums[t - off] : 0u;
    __syncthreads();
    sums[t] += u2;
    __syncthreads();
  }
  unsigned run = sums[t] - rs;   // exclusive base for bin t
  for (int b = 0; b < NBLK; ++b) {
    unsigned tmp = hist[t * NBLK + b];
    hist[t * NBLK + b] = run;
    run += tmp;
  }
}

__global__ void k_radix_scatter(const unsigned* __restrict__ key, const int* __restrict__ pay,
                                int n, int shift, const unsigned* __restrict__ hist,
                                unsigned* __restrict__ keyo, int* __restrict__ payo) {
  __shared__ unsigned mask[256][8];
  __shared__ unsigned rbase[256];
  int t = threadIdx.x;
  rbase[t] = hist[t * NBLK + blockIdx.x];
  __syncthreads();
  int base = blockIdx.x * BE;
  for (int tile = 0; tile < BE / 256; ++tile) {
    for (int wq = 0; wq < 8; ++wq) mask[t][wq] = 0u;
    __syncthreads();
    int idx = base + tile * 256 + t;
    unsigned k = 0; int bin = 0; int valid = (idx < n);
    if (valid) {
      k = key[idx];
      bin = (k >> shift) & 255;
      atomicOr(&mask[bin][t >> 5], 1u << (t & 31));
    }
    __syncthreads();
    if (valid) {
      int w = t >> 5;
      unsigned r = 0;
      for (int w2 = 0; w2 < w; ++w2) r += __popc(mask[bin][w2]);
      r += __popc(mask[bin][w] & ((1u << (t & 31)) - 1u));
      unsigned pos = rbase[bin] + r;
      keyo[pos] = k;
      payo[pos] = pay[idx];
    }
    __syncthreads();
    unsigned c = 0;
    for (int wq = 0; wq < 8; ++wq) c += __popc(mask[t][wq]);
    rbase[t] += c;
    __syncthreads();
  }
}

// ---------- K14: gather sorted endpoints + packed worklist + zero take ----------
// packed entry: (p << 30) | (s << 15) | d   with p = sorted position (= priority)
__global__ void k_gather_sorted(const int* __restrict__ pay, const int* __restrict__ ei,
                                int* __restrict__ ss, int* __restrict__ dd,
                                unsigned long long* __restrict__ wl,
                                unsigned char* __restrict__ take) {
  int i = blockIdx.x * blockDim.x + threadIdx.x;
  if (i >= N_EDGES) return;
  int o = pay[i];
  int s = ei[o];
  int d = ei[N_EDGES + o];
  ss[i] = s;
  dd[i] = d;
  wl[i] = ((unsigned long long)i << 30) | ((unsigned long long)(unsigned)s << 15)
        | (unsigned long long)(unsigned)d;
  take[i] = 0;
}

// ---------- K16: persistent single-block EXACT sequential greedy matching ----------
// Chunked: 16 waves stage 4096 sorted edges into LDS + per-64-group alive masks
// (avail[s]&&avail[d], exact behind a barrier). Wave 0 then resolves the chunk
// bit-exactly sequentially: skip dead groups via one ballot, per nonempty group
// run the ballot loop (one iteration per TAKE; intra-group conflicts killed in
// registers, cross-group conflicts caught by the avail re-check at group start).
// Work ~ #takes (~10k), NOT chain-depth (~thousands) -- the R1-R4 bottleneck.
__global__ __launch_bounds__(1024) void k_match(const unsigned long long* __restrict__ wl,
                                                unsigned char* __restrict__ take,
                                                int* __restrict__ g_avail) {
  __shared__ unsigned char avail[N_NODES];            // 20000 B
  __shared__ unsigned long long cbuf[CHUNK];          // 32768 B
  __shared__ unsigned long long gmask[64];            // 512 B
  int t = threadIdx.x;
  int lane = t & 63, wid = t >> 6;
  for (int n = t; n < N_NODES; n += 1024) avail[n] = 1;
  __syncthreads();
  for (int c = 0; c < NCHUNK; ++c) {
    int base = c * CHUNK;
    // stage: wave w handles groups w, w+16, w+32, w+48
    for (int g = wid; g < 64; g += 16) {
      int i = base + g * 64 + lane;
      unsigned long long v = (i < N_EDGES) ? wl[i] : ~0ull;
      cbuf[g * 64 + lane] = v;
      int d = (int)(v & 0x7FFFu);
      int s = (int)((v >> 15) & 0x7FFFu);
      bool alive = (i < N_EDGES) && avail[s] && avail[d];
      unsigned long long m = __ballot(alive);
      if (lane == 0) gmask[g] = m;
    }
    __syncthreads();
    // resolve: wave 0 only, exact greedy order (groups ascending, lanes ascending)
    if (wid == 0) {
      unsigned long long mym = gmask[lane];
      unsigned long long nz = __ballot(mym != 0ull);
      while (nz) {
        int g = __ffsll((long long)nz) - 1;
        nz &= nz - 1;
        unsigned long long m = __shfl(mym, g);
        unsigned long long v = cbuf[g * 64 + lane];
        int d = (int)(v & 0x7FFFu);
        int s = (int)((v >> 15) & 0x7FFFu);
        // re-check avail: takes from earlier groups of THIS chunk may have
        // invalidated the staged mask
        bool alive = ((m >> lane) & 1ull) && avail[s] && avail[d];
        unsigned long long am = __ballot(alive);
        while (am) {
          int j = __ffsll((long long)am) - 1;
          int sj = __shfl(s, j), dj = __shfl(d, j);
          if (lane == j) {
            take[(unsigned)(v >> 30)] = 1;
            avail[s] = 0; avail[d] = 0;
          }
          alive = alive && !(s == sj || s == dj || d == sj || d == dj);
          am = __ballot(alive);
        }
      }
    }
    __syncthreads();
  }
  for (int n = t; n < N_NODES; n += 1024) g_avail[n] = avail[n];
}

// ---------- K17/K17b: partial sums ----------
__global__ void k_take_part(const unsigned char* __restrict__ take, unsigned* __restrict__ tpart) {
  __shared__ unsigned s[256];
  int t = threadIdx.x; int base = blockIdx.x * BE;
  unsigned c = 0;
  for (int j = t; j < BE; j += 256) { int idx = base + j; if (idx < N_EDGES) c += take[idx]; }
  s[t] = c; __syncthreads();
  for (int off = 128; off > 0; off >>= 1) { if (t < off) s[t] += s[t + off]; __syncthreads(); }
  if (t == 0) tpart[blockIdx.x] = s[0];
}

__global__ void k_avail_part(const int* __restrict__ g_avail, unsigned* __restrict__ apart) {
  __shared__ unsigned s[256];
  int t = threadIdx.x; int base = blockIdx.x * BE;
  unsigned c = 0;
  for (int j = t; j < BE; j += 256) { int idx = base + j; if (idx < N_NODES) c += (unsigned)g_avail[idx]; }
  s[t] = c; __syncthreads();
  for (int off = 128; off > 0; off >>= 1) { if (t < off) s[t] += s[t + off]; __syncthreads(); }
  if (t == 0) apart[blockIdx.x] = s[0];
}

// ---------- K18: scan partials, compute n_matched / num_clusters ----------
__global__ void k_scan_parts(unsigned* __restrict__ tpart, unsigned* __restrict__ apart,
                             int* __restrict__ scal) {
  __shared__ unsigned arr[512];
  int t = threadIdx.x;   // 512 threads
  unsigned v = (t < NBLK) ? tpart[t] : 0u;
  arr[t] = v;
  __syncthreads();
  for (int off = 1; off < 512; off <<= 1) {
    unsigned u2 = (t >= off) ? arr[t - off] : 0u;
    __syncthreads();
    arr[t] += u2;
    __syncthreads();
  }
  unsigned excl = arr[t] - v;
  if (t < NBLK) tpart[t] = excl;
  unsigned nm = arr[511];
  __syncthreads();
  if (t == 0) {
    unsigned run = 0;
    for (int b = 0; b < NBN; ++b) { unsigned tmp = apart[b]; apart[b] = run; run += tmp; }
    scal[0] = (int)nm;            // n_matched
    scal[2] = (int)run;           // n singleton
    scal[1] = (int)(nm + run);    // num_clusters
  }
}

// ---------- K19: assign ids to matched clusters ----------
__global__ void k_finalize_taken(const unsigned char* __restrict__ take, const int* __restrict__ pay,
                                 const int* __restrict__ ss, const int* __restrict__ dd,
                                 const float* __restrict__ e, const unsigned* __restrict__ tpart,
                                 int* __restrict__ cluster, int* __restrict__ clu,
                                 int* __restrict__ clv, float* __restrict__ csc) {
  __shared__ unsigned arr[256];
  int t = threadIdx.x; int b = blockIdx.x;
  int base = b * BE + t * 4;
  unsigned char tk[4];
  unsigned c = 0;
  for (int j = 0; j < 4; ++j) {
    int p = base + j;
    tk[j] = (p < N_EDGES) ? take[p] : (unsigned char)0;
    c += tk[j];
  }
  arr[t] = c;
  __syncthreads();
  unsigned v = c;
  for (int off = 1; off < 256; off <<= 1) {
    unsigned u2 = (t >= off) ? arr[t - off] : 0u;
    __syncthreads();
    arr[t] += u2;
    __syncthreads();
  }
  unsigned id = tpart[b] + (arr[t] - v);
  for (int j = 0; j < 4; ++j) {
    int p = base + j;
    if (p < N_EDGES && tk[j]) {
      int s = ss[p], d = dd[p];
      int u = min(s, d), w = max(s, d);
      cluster[s] = (int)id; cluster[d] = (int)id;
      clu[id] = u; clv[id] = w;
      csc[id] = e[pay[p]];
      ++id;
    }
  }
}

// ---------- K19b: singleton clusters ----------
__global__ void k_finalize_single(const int* __restrict__ g_avail, const unsigned* __restrict__ apart,
                                  const int* __restrict__ scal, int* __restrict__ cluster,
                                  int* __restrict__ clu, int* __restrict__ clv,
                                  float* __restrict__ csc) {
  __shared__ unsigned arr[256];
  int t = threadIdx.x; int b = blockIdx.x;
  int base = b * BE + t * 4;
  unsigned char av[4];
  unsigned c = 0;
  for (int j = 0; j < 4; ++j) {
    int n = base + j;
    av[j] = (n < N_NODES) ? (unsigned char)g_avail[n] : (unsigned char)0;
    c += av[j];
  }
  arr[t] = c;
  __syncthreads();
  unsigned v = c;
  for (int off = 1; off < 256; off <<= 1) {
    unsigned u2 = (t >= off) ? arr[t - off] : 0u;
    __syncthreads();
    arr[t] += u2;
    __syncthreads();
  }
  unsigned id = (unsigned)scal[0] + apart[b] + (arr[t] - v);
  for (int j = 0; j < 4; ++j) {
    int n = base + j;
    if (n < N_NODES && av[j]) {
      cluster[n] = (int)id;
      clu[id] = n; clv[id] = n;
      csc[id] = 1.0f;
      ++id;
    }
  }
}

// ---------- outputs ----------
__global__ void k_out_x(const float* __restrict__ x, const int* __restrict__ clu,
                        const int* __restrict__ clv, const float* __restrict__ csc,
                        const int* __restrict__ scal, float* __restrict__ out) {
  int c = blockIdx.x; int t = threadIdx.x;
  int nc = scal[1];
  float v = 0.f;
  if (c < nc) {
    int u = clu[c], w = clv[c];
    float a = x[(size_t)u * CDIM + t];
    if (w != u) a = __fadd_rn(a, x[(size_t)w * CDIM + t]);
    v = __fmul_rn(a, csc[c]);
  }
  out[OFF_X + (size_t)c * CDIM + t] = v;
}

__global__ void k_out_edges(const int* __restrict__ ei, const int* __restrict__ cluster,
                            float* __restrict__ out) {
  int i = blockIdx.x * blockDim.x + threadIdx.x;
  if (i < 2 * N_EDGES) out[OFF_EI + i] = (float)cluster[ei[i]];
}

__global__ void k_out_rest(const int* __restrict__ cluster, const int* __restrict__ clv,
                           const int* __restrict__ batch, const int* __restrict__ scal,
                           float* __restrict__ out) {
  int i = blockIdx.x * blockDim.x + threadIdx.x;
  if (i >= N_NODES) return;
  int nc = scal[1];
  out[OFF_CL + i] = (float)cluster[i];
  out[OFF_B + i] = (i < nc) ? (float)batch[clv[i]] : 0.0f;
  if (i == 0) out[OFF_NC] = (float)nc;
}

extern "C" void kernel_launch(void* const* d_in, const int* in_sizes, int n_in,
                              void* d_out, int out_size, void* d_ws, size_t ws_size,
                              hipStream_t stream) {
  const float* x     = (const float*)d_in[0];
  const int*   ei    = (const int*)d_in[1];
  const int*   batch = (const int*)d_in[2];
  const float* lw    = (const float*)d_in[3];
  const float* lb    = (const float*)d_in[4];
  float* out = (float*)d_out;

  int* w = (int*)d_ws;
  size_t off = 0;
  auto alloc = [&](size_t n) { int* p = w + off; off += n; return p; };
  float*    p1    = (float*)alloc(N_NODES);
  float*    p2    = (float*)alloc(N_NODES);
  float*    e     = (float*)alloc(N_EDGES);
  unsigned* keyA  = (unsigned*)alloc(N_EDGES);
  unsigned* keyB  = (unsigned*)alloc(N_EDGES);
  int*      payA  = (int*)alloc(N_EDGES);
  int*      payB  = (int*)alloc(N_EDGES);
  unsigned* hist  = (unsigned*)alloc(256 * NBLK);
  off = (off + 1) & ~(size_t)1;   // align to 8B for uint64 worklist
  unsigned long long* wl = (unsigned long long*)alloc(2 * N_EDGES);
  unsigned char* take = (unsigned char*)alloc(N_EDGES / 4);
  int*      cluster = (int*)alloc(N_NODES);
  int*      clu   = (int*)alloc(N_NODES);
  int*      clv   = (int*)alloc(N_NODES);
  float*    csc   = (float*)alloc(N_NODES);
  int*      g_avail = (int*)alloc(N_NODES);
  unsigned* tpart = (unsigned*)alloc(NBLK + 1);
  unsigned* apart = (unsigned*)alloc(NBN + 1);
  int*      scal  = (int*)alloc(16);
  // after the sort finishes in (keyA,payA), keyB/payB are dead -> reuse for sorted endpoints
  int* ss = (int*)keyB;
  int* dd = payB;

  // scores
  k_node_dots<<<(N_NODES + 255) / 256, 256, 0, stream>>>(x, lw, p1, p2);
  k_edge_scores<<<(N_EDGES + 255) / 256, 256, 0, stream>>>(ei, p1, p2, lb, e, keyA, payA);

  // stable LSD radix sort, 4 passes: A->B->A->B->A
  for (int pass = 0; pass < 4; ++pass) {
    int shift = pass * 8;
    const unsigned* ki = (pass & 1) ? keyB : keyA;
    unsigned*       ko = (pass & 1) ? keyA : keyB;
    const int*      pi = (pass & 1) ? payB : payA;
    int*            po = (pass & 1) ? payA : payB;
    k_radix_hist<<<NBLK, 256, 0, stream>>>(ki, N_EDGES, shift, hist);
    k_radix_scan<<<1, 256, 0, stream>>>(hist);
    k_radix_scatter<<<NBLK, 256, 0, stream>>>(ki, pi, N_EDGES, shift, hist, ko, po);
  }

  k_gather_sorted<<<(N_EDGES + 255) / 256, 256, 0, stream>>>(payA, ei, ss, dd, wl, take);
  k_match<<<1, 1024, 0, stream>>>(wl, take, g_avail);

  k_take_part<<<NBLK, 256, 0, stream>>>(take, tpart);
  k_avail_part<<<NBN, 256, 0, stream>>>(g_avail, apart);
  k_scan_parts<<<1, 512, 0, stream>>>(tpart, apart, scal);
  k_finalize_taken<<<NBLK, 256, 0, stream>>>(take, payA, ss, dd, e, tpart, cluster, clu, clv, csc);
  k_finalize_single<<<NBN, 256, 0, stream>>>(g_avail, apart, scal, cluster, clu, clv, csc);

  k_out_x<<<N_NODES, CDIM, 0, stream>>>(x, clu, clv, csc, scal, out);
  k_out_edges<<<(2 * N_EDGES + 255) / 256, 256, 0, stream>>>(ei, cluster, out);
  k_out_rest<<<(N_NODES + 255) / 256, 256, 0, stream>>>(cluster, clv, batch, scal, out);
}

// Round 6
// 1818.587 us; speedup vs baseline: 1.2645x; 1.2645x over previous
//
#include <hip/hip_runtime.h>

#define N_NODES 20000
#define N_EDGES 320000
#define CDIM    256
#define BE      1024
#define NBLK    313      // ceil(N_EDGES/BE)
#define NBN     20       // ceil(N_NODES/BE)
#define TAILN   8192     // switch to LDS-sorted exact-serial tail at ncur <= TAILN

#define OFF_X   0
#define OFF_EI  (N_NODES*CDIM)                 // 5120000
#define OFF_CL  (OFF_EI + 2*N_EDGES)           // 5760000
#define OFF_B   (OFF_CL + N_NODES)             // 5780000
#define OFF_NC  (OFF_B + N_NODES)              // 5800000

// ---------- XLA CPU tanh: rational approximation, plain mul/add f32 ----------
__device__ __forceinline__ float xla_tanh(float x) {
  float ax = fabsf(x);
  float xc = fminf(fmaxf(x, -9.0f), 9.0f);
  float x2 = __fmul_rn(xc, xc);
  float p = -2.76076847742355e-16f;
  p = __fadd_rn(__fmul_rn(p, x2), 2.00018790482477e-13f);
  p = __fadd_rn(__fmul_rn(p, x2), -8.60467152213735e-11f);
  p = __fadd_rn(__fmul_rn(p, x2), 5.12229709037114e-08f);
  p = __fadd_rn(__fmul_rn(p, x2), 1.48572235717979e-05f);
  p = __fadd_rn(__fmul_rn(p, x2), 6.37261928875436e-04f);
  p = __fadd_rn(__fmul_rn(p, x2), 4.89352455891786e-03f);
  float num = __fmul_rn(xc, p);
  float q = 1.19825839466702e-06f;
  q = __fadd_rn(__fmul_rn(q, x2), 1.18534705686654e-04f);
  q = __fadd_rn(__fmul_rn(q, x2), 2.26843463243900e-03f);
  q = __fadd_rn(__fmul_rn(q, x2), 4.89352518554385e-03f);
  float r = num / q;   // correctly-rounded f32 divide
  return (ax < 0.0004f) ? x : r;
}

// ---------- K0: per-node partial dots, sequential-k mul+add chain ----------
__global__ void k_node_dots(const float* __restrict__ x, const float* __restrict__ w,
                            float* __restrict__ p1, float* __restrict__ p2) {
  __shared__ float sw[2*CDIM];
  for (int i = threadIdx.x; i < 2*CDIM; i += blockDim.x) sw[i] = w[i];
  __syncthreads();
  int n = blockIdx.x * blockDim.x + threadIdx.x;
  if (n >= N_NODES) return;
  const float* row = x + (size_t)n * CDIM;
  float a1 = 0.f, a2 = 0.f;
  for (int k = 0; k < CDIM; ++k) {
    float xv = row[k];
    a1 = __fadd_rn(a1, __fmul_rn(xv, sw[k]));
    a2 = __fadd_rn(a2, __fmul_rn(xv, sw[CDIM + k]));
  }
  p1[n] = a1; p2[n] = a2;
}

// ---------- K1: edge scores + sort keys ----------
__global__ void k_edge_scores(const int* __restrict__ ei, const float* __restrict__ p1,
                              const float* __restrict__ p2, const float* __restrict__ lb,
                              float* __restrict__ e, unsigned* __restrict__ keyA,
                              int* __restrict__ payA) {
  int i = blockIdx.x * blockDim.x + threadIdx.x;
  if (i >= N_EDGES) return;
  int s = ei[i], d = ei[N_EDGES + i];
  float z = __fadd_rn(__fadd_rn(p1[s], p2[d]), lb[0]);
  float ev = __fadd_rn(xla_tanh(z), 0.5f);
  e[i] = ev;
  unsigned u = __float_as_uint(ev);
  u = (u >> 31) ? ~u : (u | 0x80000000u);   // ascending-order bits of e
  keyA[i] = ~u;                              // ascending key == descending e; ties stable by idx
  payA[i] = i;
}

// ---------- radix sort (stable LSD, 4x8 bits) ----------
__global__ void k_radix_hist(const unsigned* __restrict__ key, int n, int shift,
                             unsigned* __restrict__ hist) {
  __shared__ unsigned h[256];
  int t = threadIdx.x;
  h[t] = 0;
  __syncthreads();
  int base = blockIdx.x * BE;
  for (int j = t; j < BE; j += 256) {
    int idx = base + j;
    if (idx < n) atomicAdd(&h[(key[idx] >> shift) & 255u], 1u);
  }
  __syncthreads();
  hist[t * NBLK + blockIdx.x] = h[t];
}

__global__ void k_radix_scan(unsigned* __restrict__ hist) {
  __shared__ unsigned sums[256];
  int t = threadIdx.x;
  unsigned rs = 0;
  for (int b = 0; b < NBLK; ++b) rs += hist[t * NBLK + b];
  sums[t] = rs;
  __syncthreads();
  for (int off = 1; off < 256; off <<= 1) {
    unsigned u2 = (t >= off) ? sums[t - off] : 0u;
    __syncthreads();
    sums[t] += u2;
    __syncthreads();
  }
  unsigned run = sums[t] - rs;   // exclusive base for bin t
  for (int b = 0; b < NBLK; ++b) {
    unsigned tmp = hist[t * NBLK + b];
    hist[t * NBLK + b] = run;
    run += tmp;
  }
}

__global__ void k_radix_scatter(const unsigned* __restrict__ key, const int* __restrict__ pay,
                                int n, int shift, const unsigned* __restrict__ hist,
                                unsigned* __restrict__ keyo, int* __restrict__ payo) {
  __shared__ unsigned mask[256][8];
  __shared__ unsigned rbase[256];
  int t = threadIdx.x;
  rbase[t] = hist[t * NBLK + blockIdx.x];
  __syncthreads();
  int base = blockIdx.x * BE;
  for (int tile = 0; tile < BE / 256; ++tile) {
    for (int wq = 0; wq < 8; ++wq) mask[t][wq] = 0u;
    __syncthreads();
    int idx = base + tile * 256 + t;
    unsigned k = 0; int bin = 0; int valid = (idx < n);
    if (valid) {
      k = key[idx];
      bin = (k >> shift) & 255;
      atomicOr(&mask[bin][t >> 5], 1u << (t & 31));
    }
    __syncthreads();
    if (valid) {
      int w = t >> 5;
      unsigned r = 0;
      for (int w2 = 0; w2 < w; ++w2) r += __popc(mask[bin][w2]);
      r += __popc(mask[bin][w] & ((1u << (t & 31)) - 1u));
      unsigned pos = rbase[bin] + r;
      keyo[pos] = k;
      payo[pos] = pay[idx];
    }
    __syncthreads();
    unsigned c = 0;
    for (int wq = 0; wq < 8; ++wq) c += __popc(mask[t][wq]);
    rbase[t] += c;
    __syncthreads();
  }
}

// ---------- K14: gather sorted endpoints + packed worklist + zero take ----------
// packed entry: (p << 30) | (s << 15) | d   with p = sorted position (= priority)
__global__ void k_gather_sorted(const int* __restrict__ pay, const int* __restrict__ ei,
                                int* __restrict__ ss, int* __restrict__ dd,
                                unsigned long long* __restrict__ wlA,
                                unsigned char* __restrict__ take) {
  int i = blockIdx.x * blockDim.x + threadIdx.x;
  if (i >= N_EDGES) return;
  int o = pay[i];
  int s = ei[o];
  int d = ei[N_EDGES + o];
  ss[i] = s;
  dd[i] = d;
  wlA[i] = ((unsigned long long)i << 30) | ((unsigned long long)(unsigned)s << 15)
         | (unsigned long long)(unsigned)d;
  take[i] = 0;
}

// ---------- K16: persistent single-block greedy matching (hybrid) ----------
// Bulk (ncur > TAILN): parallel fixed point of "take edge iff min-priority alive
// edge at both endpoints" (== sequential greedy subset), minp/avail in LDS,
// round-tagged keys (no reset pass), unordered wave-aggregated compaction.
// This phase collapses 320k -> ~TAILN in the cheap fast-decay regime.
// Tail (ncur <= TAILN): bitonic-sort survivors in LDS by priority (packed-u64
// ascending == priority order) and resolve EXACTLY sequentially with wave 0
// (one ballot-iteration per take). Avoids the ~2000 near-empty linger rounds
// (R3/R4 bottleneck) AND the dead-group scanning of full-serial (R5 bottleneck).
// Tail buffer reuses minp's 80KB (dead after rounds).
__global__ __launch_bounds__(1024) void k_match(unsigned long long* __restrict__ wlA,
                                                unsigned long long* __restrict__ wlB,
                                                unsigned char* __restrict__ take,
                                                int* __restrict__ g_avail) {
  __shared__ unsigned long long smem64[N_NODES / 2];   // 80000 B: minp, later tail buf
  __shared__ unsigned char avail[N_NODES];             // 20000 B
  __shared__ int s_cnt[2];
  unsigned* minp = (unsigned*)smem64;
  unsigned long long* tailb = smem64;                  // 8192 * 8B = 64KB subset
  int t = threadIdx.x;
  int lane = t & 63;
  for (int n = t; n < N_NODES; n += 1024) { avail[n] = 1; minp[n] = 0xFFFFFFFFu; }
  __syncthreads();
  int ncur = N_EDGES;
  unsigned long long* cur = wlA;
  unsigned long long* nxt = wlB;
  for (int round = 0; round < 8191 && ncur > TAILN; ++round) {
    unsigned tag = (unsigned)(8190 - round) << 19;
    int par = round & 1;
    if (t == 0) s_cnt[par] = 0;
    // phase 1: alive edges bid for their endpoints (LDS atomics)
    for (int i = t; i < ncur; i += 1024) {
      unsigned long long v = cur[i];
      int d = (int)(v & 0x7FFFu);
      int s = (int)((v >> 15) & 0x7FFFu);
      if (avail[s] && avail[d]) {
        unsigned key = tag | (unsigned)(v >> 30);
        atomicMin(&minp[s], key);
        atomicMin(&minp[d], key);
      }
    }
    __syncthreads();   // bids done + counter reset visible
    // phase 2: take local double-minima; unordered wave-aggregated compaction
    int niter = (ncur + 1023) >> 10;
    for (int it = 0; it < niter; ++it) {
      int i = (it << 10) + t;
      int keep = 0; unsigned long long v = 0;
      if (i < ncur) {
        v = cur[i];
        int d = (int)(v & 0x7FFFu);
        int s = (int)((v >> 15) & 0x7FFFu);
        if (avail[s] && avail[d]) {
          unsigned p = (unsigned)(v >> 30);
          unsigned key = tag | p;
          if (minp[s] == key && minp[d] == key) {
            take[p] = 1; avail[s] = 0; avail[d] = 0;
          } else keep = 1;
        }
      }
      unsigned long long bal = __ballot(keep);
      int cnt = __popcll(bal);
      if (cnt) {
        int leader = __ffsll(bal) - 1;
        int base = 0;
        if (lane == leader) base = atomicAdd(&s_cnt[par], cnt);
        base = __shfl(base, leader);
        if (keep) {
          int wr = __popcll(bal & ((1ull << lane) - 1ull));
          nxt[base + wr] = v;
        }
      }
    }
    __syncthreads();   // nxt + avail + counter final
    ncur = s_cnt[par];
    unsigned long long* tmp = cur; cur = nxt; nxt = tmp;
  }
  // ---- tail: sorted sequential finish (bit-exact sequential greedy) ----
  if (ncur > 0) {
    __syncthreads();   // minp reads fully done before reusing smem64 as tailb
    for (int i = t; i < TAILN; i += 1024) tailb[i] = (i < ncur) ? cur[i] : ~0ull;
    __syncthreads();
    // bitonic ascending sort over TAILN (keys distinct: priority in top bits)
    for (int k = 2; k <= TAILN; k <<= 1) {
      for (int j = k >> 1; j > 0; j >>= 1) {
        for (int i = t; i < TAILN; i += 1024) {
          int ixj = i ^ j;
          if (ixj > i) {
            unsigned long long a = tailb[i], b = tailb[ixj];
            bool up = ((i & k) == 0);
            if ((a > b) == up) { tailb[i] = b; tailb[ixj] = a; }
          }
        }
        __syncthreads();
      }
    }
    // wave 0 resolves in priority order: one ballot-iteration per taken edge
    if (t < 64) {
      int ngroups = (ncur + 63) >> 6;
      for (int g = 0; g < ngroups; ++g) {
        int i = (g << 6) + lane;
        unsigned long long v = tailb[i];
        int d = (int)(v & 0x7FFFu);
        int s = (int)((v >> 15) & 0x7FFFu);
        unsigned p = (unsigned)(v >> 30);
        bool alive = (i < ncur) && avail[s] && avail[d];
        unsigned long long am = __ballot(alive);
        while (am) {
          int j = __ffsll((long long)am) - 1;
          int sj = __shfl(s, j), dj = __shfl(d, j);
          if (lane == j) { take[p] = 1; }
          bool kill = alive && (s == sj || s == dj || d == sj || d == dj);
          if (lane == j) { avail[s] = 0; avail[d] = 0; }
          alive = alive && !kill;   // kills lane j too (s==sj)
          am = __ballot(alive);
        }
      }
    }
    __syncthreads();
  }
  for (int n = t; n < N_NODES; n += 1024) g_avail[n] = avail[n];
}

// ---------- K17/K17b: partial sums ----------
__global__ void k_take_part(const unsigned char* __restrict__ take, unsigned* __restrict__ tpart) {
  __shared__ unsigned s[256];
  int t = threadIdx.x; int base = blockIdx.x * BE;
  unsigned c = 0;
  for (int j = t; j < BE; j += 256) { int idx = base + j; if (idx < N_EDGES) c += take[idx]; }
  s[t] = c; __syncthreads();
  for (int off = 128; off > 0; off >>= 1) { if (t < off) s[t] += s[t + off]; __syncthreads(); }
  if (t == 0) tpart[blockIdx.x] = s[0];
}

__global__ void k_avail_part(const int* __restrict__ g_avail, unsigned* __restrict__ apart) {
  __shared__ unsigned s[256];
  int t = threadIdx.x; int base = blockIdx.x * BE;
  unsigned c = 0;
  for (int j = t; j < BE; j += 256) { int idx = base + j; if (idx < N_NODES) c += (unsigned)g_avail[idx]; }
  s[t] = c; __syncthreads();
  for (int off = 128; off > 0; off >>= 1) { if (t < off) s[t] += s[t + off]; __syncthreads(); }
  if (t == 0) apart[blockIdx.x] = s[0];
}

// ---------- K18: scan partials, compute n_matched / num_clusters ----------
__global__ void k_scan_parts(unsigned* __restrict__ tpart, unsigned* __restrict__ apart,
                             int* __restrict__ scal) {
  __shared__ unsigned arr[512];
  int t = threadIdx.x;   // 512 threads
  unsigned v = (t < NBLK) ? tpart[t] : 0u;
  arr[t] = v;
  __syncthreads();
  for (int off = 1; off < 512; off <<= 1) {
    unsigned u2 = (t >= off) ? arr[t - off] : 0u;
    __syncthreads();
    arr[t] += u2;
    __syncthreads();
  }
  unsigned excl = arr[t] - v;
  if (t < NBLK) tpart[t] = excl;
  unsigned nm = arr[511];
  __syncthreads();
  if (t == 0) {
    unsigned run = 0;
    for (int b = 0; b < NBN; ++b) { unsigned tmp = apart[b]; apart[b] = run; run += tmp; }
    scal[0] = (int)nm;            // n_matched
    scal[2] = (int)run;           // n singleton
    scal[1] = (int)(nm + run);    // num_clusters
  }
}

// ---------- K19: assign ids to matched clusters ----------
__global__ void k_finalize_taken(const unsigned char* __restrict__ take, const int* __restrict__ pay,
                                 const int* __restrict__ ss, const int* __restrict__ dd,
                                 const float* __restrict__ e, const unsigned* __restrict__ tpart,
                                 int* __restrict__ cluster, int* __restrict__ clu,
                                 int* __restrict__ clv, float* __restrict__ csc) {
  __shared__ unsigned arr[256];
  int t = threadIdx.x; int b = blockIdx.x;
  int base = b * BE + t * 4;
  unsigned char tk[4];
  unsigned c = 0;
  for (int j = 0; j < 4; ++j) {
    int p = base + j;
    tk[j] = (p < N_EDGES) ? take[p] : (unsigned char)0;
    c += tk[j];
  }
  arr[t] = c;
  __syncthreads();
  unsigned v = c;
  for (int off = 1; off < 256; off <<= 1) {
    unsigned u2 = (t >= off) ? arr[t - off] : 0u;
    __syncthreads();
    arr[t] += u2;
    __syncthreads();
  }
  unsigned id = tpart[b] + (arr[t] - v);
  for (int j = 0; j < 4; ++j) {
    int p = base + j;
    if (p < N_EDGES && tk[j]) {
      int s = ss[p], d = dd[p];
      int u = min(s, d), w = max(s, d);
      cluster[s] = (int)id; cluster[d] = (int)id;
      clu[id] = u; clv[id] = w;
      csc[id] = e[pay[p]];
      ++id;
    }
  }
}

// ---------- K19b: singleton clusters ----------
__global__ void k_finalize_single(const int* __restrict__ g_avail, const unsigned* __restrict__ apart,
                                  const int* __restrict__ scal, int* __restrict__ cluster,
                                  int* __restrict__ clu, int* __restrict__ clv,
                                  float* __restrict__ csc) {
  __shared__ unsigned arr[256];
  int t = threadIdx.x; int b = blockIdx.x;
  int base = b * BE + t * 4;
  unsigned char av[4];
  unsigned c = 0;
  for (int j = 0; j < 4; ++j) {
    int n = base + j;
    av[j] = (n < N_NODES) ? (unsigned char)g_avail[n] : (unsigned char)0;
    c += av[j];
  }
  arr[t] = c;
  __syncthreads();
  unsigned v = c;
  for (int off = 1; off < 256; off <<= 1) {
    unsigned u2 = (t >= off) ? arr[t - off] : 0u;
    __syncthreads();
    arr[t] += u2;
    __syncthreads();
  }
  unsigned id = (unsigned)scal[0] + apart[b] + (arr[t] - v);
  for (int j = 0; j < 4; ++j) {
    int n = base + j;
    if (n < N_NODES && av[j]) {
      cluster[n] = (int)id;
      clu[id] = n; clv[id] = n;
      csc[id] = 1.0f;
      ++id;
    }
  }
}

// ---------- outputs ----------
__global__ void k_out_x(const float* __restrict__ x, const int* __restrict__ clu,
                        const int* __restrict__ clv, const float* __restrict__ csc,
                        const int* __restrict__ scal, float* __restrict__ out) {
  int c = blockIdx.x; int t = threadIdx.x;
  int nc = scal[1];
  float v = 0.f;
  if (c < nc) {
    int u = clu[c], w = clv[c];
    float a = x[(size_t)u * CDIM + t];
    if (w != u) a = __fadd_rn(a, x[(size_t)w * CDIM + t]);
    v = __fmul_rn(a, csc[c]);
  }
  out[OFF_X + (size_t)c * CDIM + t] = v;
}

__global__ void k_out_edges(const int* __restrict__ ei, const int* __restrict__ cluster,
                            float* __restrict__ out) {
  int i = blockIdx.x * blockDim.x + threadIdx.x;
  if (i < 2 * N_EDGES) out[OFF_EI + i] = (float)cluster[ei[i]];
}

__global__ void k_out_rest(const int* __restrict__ cluster, const int* __restrict__ clv,
                           const int* __restrict__ batch, const int* __restrict__ scal,
                           float* __restrict__ out) {
  int i = blockIdx.x * blockDim.x + threadIdx.x;
  if (i >= N_NODES) return;
  int nc = scal[1];
  out[OFF_CL + i] = (float)cluster[i];
  out[OFF_B + i] = (i < nc) ? (float)batch[clv[i]] : 0.0f;
  if (i == 0) out[OFF_NC] = (float)nc;
}

extern "C" void kernel_launch(void* const* d_in, const int* in_sizes, int n_in,
                              void* d_out, int out_size, void* d_ws, size_t ws_size,
                              hipStream_t stream) {
  const float* x     = (const float*)d_in[0];
  const int*   ei    = (const int*)d_in[1];
  const int*   batch = (const int*)d_in[2];
  const float* lw    = (const float*)d_in[3];
  const float* lb    = (const float*)d_in[4];
  float* out = (float*)d_out;

  int* w = (int*)d_ws;
  size_t off = 0;
  auto alloc = [&](size_t n) { int* p = w + off; off += n; return p; };
  float*    p1    = (float*)alloc(N_NODES);
  float*    p2    = (float*)alloc(N_NODES);
  float*    e     = (float*)alloc(N_EDGES);
  unsigned* keyA  = (unsigned*)alloc(N_EDGES);
  unsigned* keyB  = (unsigned*)alloc(N_EDGES);
  int*      payA  = (int*)alloc(N_EDGES);
  int*      payB  = (int*)alloc(N_EDGES);
  unsigned* hist  = (unsigned*)alloc(256 * NBLK);
  off = (off + 1) & ~(size_t)1;   // align to 8B for uint64 worklists
  unsigned long long* wlA = (unsigned long long*)alloc(2 * N_EDGES);
  unsigned long long* wlB = (unsigned long long*)alloc(2 * N_EDGES);
  unsigned char* take = (unsigned char*)alloc(N_EDGES / 4);
  int*      cluster = (int*)alloc(N_NODES);
  int*      clu   = (int*)alloc(N_NODES);
  int*      clv   = (int*)alloc(N_NODES);
  float*    csc   = (float*)alloc(N_NODES);
  int*      g_avail = (int*)alloc(N_NODES);
  unsigned* tpart = (unsigned*)alloc(NBLK + 1);
  unsigned* apart = (unsigned*)alloc(NBN + 1);
  int*      scal  = (int*)alloc(16);
  // after the sort finishes in (keyA,payA), keyB/payB are dead -> reuse for sorted endpoints
  int* ss = (int*)keyB;
  int* dd = payB;

  // scores
  k_node_dots<<<(N_NODES + 255) / 256, 256, 0, stream>>>(x, lw, p1, p2);
  k_edge_scores<<<(N_EDGES + 255) / 256, 256, 0, stream>>>(ei, p1, p2, lb, e, keyA, payA);

  // stable LSD radix sort, 4 passes: A->B->A->B->A
  for (int pass = 0; pass < 4; ++pass) {
    int shift = pass * 8;
    const unsigned* ki = (pass & 1) ? keyB : keyA;
    unsigned*       ko = (pass & 1) ? keyA : keyB;
    const int*      pi = (pass & 1) ? payB : payA;
    int*            po = (pass & 1) ? payA : payB;
    k_radix_hist<<<NBLK, 256, 0, stream>>>(ki, N_EDGES, shift, hist);
    k_radix_scan<<<1, 256, 0, stream>>>(hist);
    k_radix_scatter<<<NBLK, 256, 0, stream>>>(ki, pi, N_EDGES, shift, hist, ko, po);
  }

  k_gather_sorted<<<(N_EDGES + 255) / 256, 256, 0, stream>>>(payA, ei, ss, dd, wlA, take);
  k_match<<<1, 1024, 0, stream>>>(wlA, wlB, take, g_avail);

  k_take_part<<<NBLK, 256, 0, stream>>>(take, tpart);
  k_avail_part<<<NBN, 256, 0, stream>>>(g_avail, apart);
  k_scan_parts<<<1, 512, 0, stream>>>(tpart, apart, scal);
  k_finalize_taken<<<NBLK, 256, 0, stream>>>(take, payA, ss, dd, e, tpart, cluster, clu, clv, csc);
  k_finalize_single<<<NBN, 256, 0, stream>>>(g_avail, apart, scal, cluster, clu, clv, csc);

  k_out_x<<<N_NODES, CDIM, 0, stream>>>(x, clu, clv, csc, scal, out);
  k_out_edges<<<(2 * N_EDGES + 255) / 256, 256, 0, stream>>>(ei, cluster, out);
  k_out_rest<<<(N_NODES + 255) / 256, 256, 0, stream>>>(cluster, clv, batch, scal, out);
}

// Round 7
// 1360.008 us; speedup vs baseline: 1.6908x; 1.3372x over previous
//
#include <hip/hip_runtime.h>

#define N_NODES 20000
#define N_EDGES 320000
#define CDIM    256
#define BE      1024
#define NBLK    313      // ceil(N_EDGES/BE)
#define NBN     20       // ceil(N_NODES/BE)
#define CH      8192     // serial-match chunk size
#define NGRP    (CH/64)  // 128 raw groups per chunk
#define NCH     ((N_EDGES + CH - 1) / CH)   // 40

#define OFF_X   0
#define OFF_EI  (N_NODES*CDIM)                 // 5120000
#define OFF_CL  (OFF_EI + 2*N_EDGES)           // 5760000
#define OFF_B   (OFF_CL + N_NODES)             // 5780000
#define OFF_NC  (OFF_B + N_NODES)              // 5800000

// ---------- XLA CPU tanh: rational approximation, plain mul/add f32 ----------
__device__ __forceinline__ float xla_tanh(float x) {
  float ax = fabsf(x);
  float xc = fminf(fmaxf(x, -9.0f), 9.0f);
  float x2 = __fmul_rn(xc, xc);
  float p = -2.76076847742355e-16f;
  p = __fadd_rn(__fmul_rn(p, x2), 2.00018790482477e-13f);
  p = __fadd_rn(__fmul_rn(p, x2), -8.60467152213735e-11f);
  p = __fadd_rn(__fmul_rn(p, x2), 5.12229709037114e-08f);
  p = __fadd_rn(__fmul_rn(p, x2), 1.48572235717979e-05f);
  p = __fadd_rn(__fmul_rn(p, x2), 6.37261928875436e-04f);
  p = __fadd_rn(__fmul_rn(p, x2), 4.89352455891786e-03f);
  float num = __fmul_rn(xc, p);
  float q = 1.19825839466702e-06f;
  q = __fadd_rn(__fmul_rn(q, x2), 1.18534705686654e-04f);
  q = __fadd_rn(__fmul_rn(q, x2), 2.26843463243900e-03f);
  q = __fadd_rn(__fmul_rn(q, x2), 4.89352518554385e-03f);
  float r = num / q;   // correctly-rounded f32 divide
  return (ax < 0.0004f) ? x : r;
}

// ---------- K0: per-node partial dots, sequential-k mul+add chain ----------
__global__ void k_node_dots(const float* __restrict__ x, const float* __restrict__ w,
                            float* __restrict__ p1, float* __restrict__ p2) {
  __shared__ float sw[2*CDIM];
  for (int i = threadIdx.x; i < 2*CDIM; i += blockDim.x) sw[i] = w[i];
  __syncthreads();
  int n = blockIdx.x * blockDim.x + threadIdx.x;
  if (n >= N_NODES) return;
  const float* row = x + (size_t)n * CDIM;
  float a1 = 0.f, a2 = 0.f;
  for (int k = 0; k < CDIM; ++k) {
    float xv = row[k];
    a1 = __fadd_rn(a1, __fmul_rn(xv, sw[k]));
    a2 = __fadd_rn(a2, __fmul_rn(xv, sw[CDIM + k]));
  }
  p1[n] = a1; p2[n] = a2;
}

// ---------- K1: edge scores + sort keys ----------
__global__ void k_edge_scores(const int* __restrict__ ei, const float* __restrict__ p1,
                              const float* __restrict__ p2, const float* __restrict__ lb,
                              float* __restrict__ e, unsigned* __restrict__ keyA,
                              int* __restrict__ payA) {
  int i = blockIdx.x * blockDim.x + threadIdx.x;
  if (i >= N_EDGES) return;
  int s = ei[i], d = ei[N_EDGES + i];
  float z = __fadd_rn(__fadd_rn(p1[s], p2[d]), lb[0]);
  float ev = __fadd_rn(xla_tanh(z), 0.5f);
  e[i] = ev;
  unsigned u = __float_as_uint(ev);
  u = (u >> 31) ? ~u : (u | 0x80000000u);   // ascending-order bits of e
  keyA[i] = ~u;                              // ascending key == descending e; ties stable by idx
  payA[i] = i;
}

// ---------- radix sort (stable LSD, 4x8 bits) ----------
__global__ void k_radix_hist(const unsigned* __restrict__ key, int n, int shift,
                             unsigned* __restrict__ hist) {
  __shared__ unsigned h[256];
  int t = threadIdx.x;
  h[t] = 0;
  __syncthreads();
  int base = blockIdx.x * BE;
  for (int j = t; j < BE; j += 256) {
    int idx = base + j;
    if (idx < n) atomicAdd(&h[(key[idx] >> shift) & 255u], 1u);
  }
  __syncthreads();
  hist[t * NBLK + blockIdx.x] = h[t];
}

__global__ void k_radix_scan(unsigned* __restrict__ hist) {
  __shared__ unsigned sums[256];
  int t = threadIdx.x;
  unsigned rs = 0;
  for (int b = 0; b < NBLK; ++b) rs += hist[t * NBLK + b];
  sums[t] = rs;
  __syncthreads();
  for (int off = 1; off < 256; off <<= 1) {
    unsigned u2 = (t >= off) ? sums[t - off] : 0u;
    __syncthreads();
    sums[t] += u2;
    __syncthreads();
  }
  unsigned run = sums[t] - rs;   // exclusive base for bin t
  for (int b = 0; b < NBLK; ++b) {
    unsigned tmp = hist[t * NBLK + b];
    hist[t * NBLK + b] = run;
    run += tmp;
  }
}

__global__ void k_radix_scatter(const unsigned* __restrict__ key, const int* __restrict__ pay,
                                int n, int shift, const unsigned* __restrict__ hist,
                                unsigned* __restrict__ keyo, int* __restrict__ payo) {
  __shared__ unsigned mask[256][8];
  __shared__ unsigned rbase[256];
  int t = threadIdx.x;
  rbase[t] = hist[t * NBLK + blockIdx.x];
  __syncthreads();
  int base = blockIdx.x * BE;
  for (int tile = 0; tile < BE / 256; ++tile) {
    for (int wq = 0; wq < 8; ++wq) mask[t][wq] = 0u;
    __syncthreads();
    int idx = base + tile * 256 + t;
    unsigned k = 0; int bin = 0; int valid = (idx < n);
    if (valid) {
      k = key[idx];
      bin = (k >> shift) & 255;
      atomicOr(&mask[bin][t >> 5], 1u << (t & 31));
    }
    __syncthreads();
    if (valid) {
      int w = t >> 5;
      unsigned r = 0;
      for (int w2 = 0; w2 < w; ++w2) r += __popc(mask[bin][w2]);
      r += __popc(mask[bin][w] & ((1u << (t & 31)) - 1u));
      unsigned pos = rbase[bin] + r;
      keyo[pos] = k;
      payo[pos] = pay[idx];
    }
    __syncthreads();
    unsigned c = 0;
    for (int wq = 0; wq < 8; ++wq) c += __popc(mask[t][wq]);
    rbase[t] += c;
    __syncthreads();
  }
}

// ---------- K14: gather sorted endpoints + packed worklist + zero take ----------
// packed entry: (p << 30) | (s << 15) | d   with p = sorted position (= priority)
__global__ void k_gather_sorted(const int* __restrict__ pay, const int* __restrict__ ei,
                                int* __restrict__ ss, int* __restrict__ dd,
                                unsigned long long* __restrict__ wl,
                                unsigned char* __restrict__ take) {
  int i = blockIdx.x * blockDim.x + threadIdx.x;
  if (i >= N_EDGES) return;
  int o = pay[i];
  int s = ei[o];
  int d = ei[N_EDGES + o];
  ss[i] = s;
  dd[i] = d;
  wl[i] = ((unsigned long long)i << 30) | ((unsigned long long)(unsigned)s << 15)
        | (unsigned long long)(unsigned)d;
  take[i] = 0;
}

// ---------- K16: persistent single-block EXACT sequential greedy matching ----------
// Chunked over the sorted edge list (8192/chunk). Per chunk:
//  1) 16 waves stage + alive-check (avail both endpoints) and ORDER-PRESERVING
//     compact alive edges into LDS (dead edges never revive -> safe to drop).
//  2) 16 waves build per-edge intra-group KILL-MASKS (bit j>i set if edge j
//     shares an endpoint with edge i; self bit included).
//  3) Wave 0 walks alive groups in order: recheck avail (cross-group kills
//     within the chunk), ballot -> am, then serial core per TAKE only:
//     j=ffs(am); tk|=1<<j; am&=~kmask[j]  (one LDS broadcast read ~55cy/take).
//     Taken lanes then clear avail and set take[] in parallel.
// Take-set == sequential greedy (order preserved; all earlier-edge conflicts
// covered by compaction-drop + recheck + kill-masks) -> outputs bit-identical.
__global__ __launch_bounds__(1024) void k_match(const unsigned long long* __restrict__ wl,
                                                unsigned char* __restrict__ take,
                                                int* __restrict__ g_avail) {
  __shared__ unsigned char avail[N_NODES];          // 20000 B
  __shared__ unsigned long long comp[CH];           // 65536 B
  __shared__ unsigned long long kmask[CH];          // 65536 B
  __shared__ unsigned gcnt[NGRP];                   // 512 B
  __shared__ unsigned gbase[NGRP];                  // 512 B
  __shared__ int s_ncomp;
  int t = threadIdx.x;
  int lane = t & 63, wid = t >> 6;
  unsigned long long lmask_lt = (lane == 0) ? 0ull : (~0ull >> (64 - lane));
  for (int n = t; n < N_NODES; n += 1024) avail[n] = 1;
  __syncthreads();
  for (int c = 0; c < NCH; ++c) {
    int base = c * CH;
    // --- 1a) stage + alive-count (wave wid owns raw groups wid*8 .. wid*8+7)
    unsigned long long myv[8];
    unsigned char myal[8];
    for (int it = 0; it < 8; ++it) {
      int rg = wid * 8 + it;
      int i = base + rg * 64 + lane;
      unsigned long long v = (i < N_EDGES) ? wl[i] : 0ull;
      bool a = false;
      if (i < N_EDGES) {
        int d = (int)(v & 0x7FFFu);
        int s = (int)((v >> 15) & 0x7FFFu);
        a = avail[s] && avail[d];
      }
      myv[it] = v; myal[it] = a ? 1 : 0;
      unsigned long long bal = __ballot(a);
      if (lane == 0) gcnt[rg] = (unsigned)__popcll(bal);
    }
    __syncthreads();
    // --- 1b) exclusive scan of 128 raw-group counts (wave 0)
    if (wid == 0) {
      unsigned a0 = gcnt[lane], a1 = gcnt[64 + lane];
      unsigned s0 = a0;
      for (int o = 1; o < 64; o <<= 1) { unsigned u = __shfl_up(s0, o); if (lane >= o) s0 += u; }
      unsigned tot0 = __shfl(s0, 63);
      unsigned s1 = a1;
      for (int o = 1; o < 64; o <<= 1) { unsigned u = __shfl_up(s1, o); if (lane >= o) s1 += u; }
      gbase[lane] = s0 - a0;
      gbase[64 + lane] = tot0 + s1 - a1;
      if (lane == 63) s_ncomp = (int)(tot0 + s1);
    }
    __syncthreads();
    // --- 1c) order-preserving writeback of alive edges
    for (int it = 0; it < 8; ++it) {
      int rg = wid * 8 + it;
      unsigned long long bal = __ballot(myal[it] != 0);
      if (myal[it]) {
        unsigned r = (unsigned)__popcll(bal & lmask_lt);
        comp[gbase[rg] + r] = myv[it];
      }
    }
    __syncthreads();
    int ncomp = s_ncomp;
    // --- 2) kill-mask build over compacted groups (16 waves round-robin)
    for (int g = wid; g * 64 < ncomp; g += 16) {
      int i = g * 64 + lane;
      unsigned long long v = (i < ncomp) ? comp[i] : 0ull;
      int d = (int)(v & 0x7FFFu);
      int s = (int)((v >> 15) & 0x7FFFu);
      unsigned long long km = 1ull << lane;   // self bit
      if (i < ncomp) {
        int glen = ncomp - g * 64; if (glen > 64) glen = 64;
        for (int j = lane + 1; j < glen; ++j) {
          unsigned long long vj = comp[g * 64 + j];   // broadcast read
          int dj = (int)(vj & 0x7FFFu);
          int sj = (int)((vj >> 15) & 0x7FFFu);
          if (sj == s || sj == d || dj == s || dj == d) km |= 1ull << j;
        }
      }
      kmask[g * 64 + lane] = km;
    }
    __syncthreads();
    // --- 3) wave-0 exact serial walk
    if (wid == 0) {
      for (int g = 0; g * 64 < ncomp; ++g) {
        int i = g * 64 + lane;
        unsigned long long v = (i < ncomp) ? comp[i] : 0ull;
        int d = (int)(v & 0x7FFFu);
        int s = (int)((v >> 15) & 0x7FFFu);
        bool alive = (i < ncomp) && avail[s] && avail[d];
        unsigned long long am = __ballot(alive);
        unsigned long long tk = 0;
        while (am) {
          int j = __ffsll((long long)am) - 1;
          tk |= 1ull << j;
          am &= ~kmask[g * 64 + j];   // kills j itself + later conflicts
        }
        if ((tk >> lane) & 1ull) {
          take[(unsigned)(v >> 30)] = 1;
          avail[s] = 0; avail[d] = 0;
        }
      }
    }
    __syncthreads();
  }
  for (int n = t; n < N_NODES; n += 1024) g_avail[n] = avail[n];
}

// ---------- K17/K17b: partial sums ----------
__global__ void k_take_part(const unsigned char* __restrict__ take, unsigned* __restrict__ tpart) {
  __shared__ unsigned s[256];
  int t = threadIdx.x; int base = blockIdx.x * BE;
  unsigned c = 0;
  for (int j = t; j < BE; j += 256) { int idx = base + j; if (idx < N_EDGES) c += take[idx]; }
  s[t] = c; __syncthreads();
  for (int off = 128; off > 0; off >>= 1) { if (t < off) s[t] += s[t + off]; __syncthreads(); }
  if (t == 0) tpart[blockIdx.x] = s[0];
}

__global__ void k_avail_part(const int* __restrict__ g_avail, unsigned* __restrict__ apart) {
  __shared__ unsigned s[256];
  int t = threadIdx.x; int base = blockIdx.x * BE;
  unsigned c = 0;
  for (int j = t; j < BE; j += 256) { int idx = base + j; if (idx < N_NODES) c += (unsigned)g_avail[idx]; }
  s[t] = c; __syncthreads();
  for (int off = 128; off > 0; off >>= 1) { if (t < off) s[t] += s[t + off]; __syncthreads(); }
  if (t == 0) apart[blockIdx.x] = s[0];
}

// ---------- K18: scan partials, compute n_matched / num_clusters ----------
__global__ void k_scan_parts(unsigned* __restrict__ tpart, unsigned* __restrict__ apart,
                             int* __restrict__ scal) {
  __shared__ unsigned arr[512];
  int t = threadIdx.x;   // 512 threads
  unsigned v = (t < NBLK) ? tpart[t] : 0u;
  arr[t] = v;
  __syncthreads();
  for (int off = 1; off < 512; off <<= 1) {
    unsigned u2 = (t >= off) ? arr[t - off] : 0u;
    __syncthreads();
    arr[t] += u2;
    __syncthreads();
  }
  unsigned excl = arr[t] - v;
  if (t < NBLK) tpart[t] = excl;
  unsigned nm = arr[511];
  __syncthreads();
  if (t == 0) {
    unsigned run = 0;
    for (int b = 0; b < NBN; ++b) { unsigned tmp = apart[b]; apart[b] = run; run += tmp; }
    scal[0] = (int)nm;            // n_matched
    scal[2] = (int)run;           // n singleton
    scal[1] = (int)(nm + run);    // num_clusters
  }
}

// ---------- K19: assign ids to matched clusters ----------
__global__ void k_finalize_taken(const unsigned char* __restrict__ take, const int* __restrict__ pay,
                                 const int* __restrict__ ss, const int* __restrict__ dd,
                                 const float* __restrict__ e, const unsigned* __restrict__ tpart,
                                 int* __restrict__ cluster, int* __restrict__ clu,
                                 int* __restrict__ clv, float* __restrict__ csc) {
  __shared__ unsigned arr[256];
  int t = threadIdx.x; int b = blockIdx.x;
  int base = b * BE + t * 4;
  unsigned char tk[4];
  unsigned c = 0;
  for (int j = 0; j < 4; ++j) {
    int p = base + j;
    tk[j] = (p < N_EDGES) ? take[p] : (unsigned char)0;
    c += tk[j];
  }
  arr[t] = c;
  __syncthreads();
  unsigned v = c;
  for (int off = 1; off < 256; off <<= 1) {
    unsigned u2 = (t >= off) ? arr[t - off] : 0u;
    __syncthreads();
    arr[t] += u2;
    __syncthreads();
  }
  unsigned id = tpart[b] + (arr[t] - v);
  for (int j = 0; j < 4; ++j) {
    int p = base + j;
    if (p < N_EDGES && tk[j]) {
      int s = ss[p], d = dd[p];
      int u = min(s, d), w = max(s, d);
      cluster[s] = (int)id; cluster[d] = (int)id;
      clu[id] = u; clv[id] = w;
      csc[id] = e[pay[p]];
      ++id;
    }
  }
}

// ---------- K19b: singleton clusters ----------
__global__ void k_finalize_single(const int* __restrict__ g_avail, const unsigned* __restrict__ apart,
                                  const int* __restrict__ scal, int* __restrict__ cluster,
                                  int* __restrict__ clu, int* __restrict__ clv,
                                  float* __restrict__ csc) {
  __shared__ unsigned arr[256];
  int t = threadIdx.x; int b = blockIdx.x;
  int base = b * BE + t * 4;
  unsigned char av[4];
  unsigned c = 0;
  for (int j = 0; j < 4; ++j) {
    int n = base + j;
    av[j] = (n < N_NODES) ? (unsigned char)g_avail[n] : (unsigned char)0;
    c += av[j];
  }
  arr[t] = c;
  __syncthreads();
  unsigned v = c;
  for (int off = 1; off < 256; off <<= 1) {
    unsigned u2 = (t >= off) ? arr[t - off] : 0u;
    __syncthreads();
    arr[t] += u2;
    __syncthreads();
  }
  unsigned id = (unsigned)scal[0] + apart[b] + (arr[t] - v);
  for (int j = 0; j < 4; ++j) {
    int n = base + j;
    if (n < N_NODES && av[j]) {
      cluster[n] = (int)id;
      clu[id] = n; clv[id] = n;
      csc[id] = 1.0f;
      ++id;
    }
  }
}

// ---------- outputs ----------
__global__ void k_out_x(const float* __restrict__ x, const int* __restrict__ clu,
                        const int* __restrict__ clv, const float* __restrict__ csc,
                        const int* __restrict__ scal, float* __restrict__ out) {
  int c = blockIdx.x; int t = threadIdx.x;
  int nc = scal[1];
  float v = 0.f;
  if (c < nc) {
    int u = clu[c], w = clv[c];
    float a = x[(size_t)u * CDIM + t];
    if (w != u) a = __fadd_rn(a, x[(size_t)w * CDIM + t]);
    v = __fmul_rn(a, csc[c]);
  }
  out[OFF_X + (size_t)c * CDIM + t] = v;
}

__global__ void k_out_edges(const int* __restrict__ ei, const int* __restrict__ cluster,
                            float* __restrict__ out) {
  int i = blockIdx.x * blockDim.x + threadIdx.x;
  if (i < 2 * N_EDGES) out[OFF_EI + i] = (float)cluster[ei[i]];
}

__global__ void k_out_rest(const int* __restrict__ cluster, const int* __restrict__ clv,
                           const int* __restrict__ batch, const int* __restrict__ scal,
                           float* __restrict__ out) {
  int i = blockIdx.x * blockDim.x + threadIdx.x;
  if (i >= N_NODES) return;
  int nc = scal[1];
  out[OFF_CL + i] = (float)cluster[i];
  out[OFF_B + i] = (i < nc) ? (float)batch[clv[i]] : 0.0f;
  if (i == 0) out[OFF_NC] = (float)nc;
}

extern "C" void kernel_launch(void* const* d_in, const int* in_sizes, int n_in,
                              void* d_out, int out_size, void* d_ws, size_t ws_size,
                              hipStream_t stream) {
  const float* x     = (const float*)d_in[0];
  const int*   ei    = (const int*)d_in[1];
  const int*   batch = (const int*)d_in[2];
  const float* lw    = (const float*)d_in[3];
  const float* lb    = (const float*)d_in[4];
  float* out = (float*)d_out;

  int* w = (int*)d_ws;
  size_t off = 0;
  auto alloc = [&](size_t n) { int* p = w + off; off += n; return p; };
  float*    p1    = (float*)alloc(N_NODES);
  float*    p2    = (float*)alloc(N_NODES);
  float*    e     = (float*)alloc(N_EDGES);
  unsigned* keyA  = (unsigned*)alloc(N_EDGES);
  unsigned* keyB  = (unsigned*)alloc(N_EDGES);
  int*      payA  = (int*)alloc(N_EDGES);
  int*      payB  = (int*)alloc(N_EDGES);
  unsigned* hist  = (unsigned*)alloc(256 * NBLK);
  off = (off + 1) & ~(size_t)1;   // align to 8B for uint64 worklist
  unsigned long long* wl = (unsigned long long*)alloc(2 * N_EDGES);
  unsigned char* take = (unsigned char*)alloc(N_EDGES / 4);
  int*      cluster = (int*)alloc(N_NODES);
  int*      clu   = (int*)alloc(N_NODES);
  int*      clv   = (int*)alloc(N_NODES);
  float*    csc   = (float*)alloc(N_NODES);
  int*      g_avail = (int*)alloc(N_NODES);
  unsigned* tpart = (unsigned*)alloc(NBLK + 1);
  unsigned* apart = (unsigned*)alloc(NBN + 1);
  int*      scal  = (int*)alloc(16);
  // after the sort finishes in (keyA,payA), keyB/payB are dead -> reuse for sorted endpoints
  int* ss = (int*)keyB;
  int* dd = payB;

  // scores
  k_node_dots<<<(N_NODES + 255) / 256, 256, 0, stream>>>(x, lw, p1, p2);
  k_edge_scores<<<(N_EDGES + 255) / 256, 256, 0, stream>>>(ei, p1, p2, lb, e, keyA, payA);

  // stable LSD radix sort, 4 passes: A->B->A->B->A
  for (int pass = 0; pass < 4; ++pass) {
    int shift = pass * 8;
    const unsigned* ki = (pass & 1) ? keyB : keyA;
    unsigned*       ko = (pass & 1) ? keyA : keyB;
    const int*      pi = (pass & 1) ? payB : payA;
    int*            po = (pass & 1) ? payA : payB;
    k_radix_hist<<<NBLK, 256, 0, stream>>>(ki, N_EDGES, shift, hist);
    k_radix_scan<<<1, 256, 0, stream>>>(hist);
    k_radix_scatter<<<NBLK, 256, 0, stream>>>(ki, pi, N_EDGES, shift, hist, ko, po);
  }

  k_gather_sorted<<<(N_EDGES + 255) / 256, 256, 0, stream>>>(payA, ei, ss, dd, wl, take);
  k_match<<<1, 1024, 0, stream>>>(wl, take, g_avail);

  k_take_part<<<NBLK, 256, 0, stream>>>(take, tpart);
  k_avail_part<<<NBN, 256, 0, stream>>>(g_avail, apart);
  k_scan_parts<<<1, 512, 0, stream>>>(tpart, apart, scal);
  k_finalize_taken<<<NBLK, 256, 0, stream>>>(take, payA, ss, dd, e, tpart, cluster, clu, clv, csc);
  k_finalize_single<<<NBN, 256, 0, stream>>>(g_avail, apart, scal, cluster, clu, clv, csc);

  k_out_x<<<N_NODES, CDIM, 0, stream>>>(x, clu, clv, csc, scal, out);
  k_out_edges<<<(2 * N_EDGES + 255) / 256, 256, 0, stream>>>(ei, cluster, out);
  k_out_rest<<<(N_NODES + 255) / 256, 256, 0, stream>>>(cluster, clv, batch, scal, out);
}

// Round 8
// 1096.992 us; speedup vs baseline: 2.0962x; 1.2398x over previous
//
#include <hip/hip_runtime.h>

#define N_NODES 20000
#define N_EDGES 320000
#define CDIM    256
#define BE      1024
#define NBLK    313      // ceil(N_EDGES/BE)
#define NBN     20       // ceil(N_NODES/BE)
#define CH      8192     // serial-match chunk size
#define NGRP    (CH/64)  // 128 raw groups per chunk
#define NCH     ((N_EDGES + CH - 1) / CH)   // 40

#define OFF_X   0
#define OFF_EI  (N_NODES*CDIM)                 // 5120000
#define OFF_CL  (OFF_EI + 2*N_EDGES)           // 5760000
#define OFF_B   (OFF_CL + N_NODES)             // 5780000
#define OFF_NC  (OFF_B + N_NODES)              // 5800000

// ---------- XLA CPU tanh: rational approximation, plain mul/add f32 ----------
__device__ __forceinline__ float xla_tanh(float x) {
  float ax = fabsf(x);
  float xc = fminf(fmaxf(x, -9.0f), 9.0f);
  float x2 = __fmul_rn(xc, xc);
  float p = -2.76076847742355e-16f;
  p = __fadd_rn(__fmul_rn(p, x2), 2.00018790482477e-13f);
  p = __fadd_rn(__fmul_rn(p, x2), -8.60467152213735e-11f);
  p = __fadd_rn(__fmul_rn(p, x2), 5.12229709037114e-08f);
  p = __fadd_rn(__fmul_rn(p, x2), 1.48572235717979e-05f);
  p = __fadd_rn(__fmul_rn(p, x2), 6.37261928875436e-04f);
  p = __fadd_rn(__fmul_rn(p, x2), 4.89352455891786e-03f);
  float num = __fmul_rn(xc, p);
  float q = 1.19825839466702e-06f;
  q = __fadd_rn(__fmul_rn(q, x2), 1.18534705686654e-04f);
  q = __fadd_rn(__fmul_rn(q, x2), 2.26843463243900e-03f);
  q = __fadd_rn(__fmul_rn(q, x2), 4.89352518554385e-03f);
  float r = num / q;   // correctly-rounded f32 divide
  return (ax < 0.0004f) ? x : r;
}

// ---------- K0: per-node partial dots, sequential-k mul+add chain ----------
__global__ void k_node_dots(const float* __restrict__ x, const float* __restrict__ w,
                            float* __restrict__ p1, float* __restrict__ p2) {
  __shared__ float sw[2*CDIM];
  for (int i = threadIdx.x; i < 2*CDIM; i += blockDim.x) sw[i] = w[i];
  __syncthreads();
  int n = blockIdx.x * blockDim.x + threadIdx.x;
  if (n >= N_NODES) return;
  const float* row = x + (size_t)n * CDIM;
  float a1 = 0.f, a2 = 0.f;
  for (int k = 0; k < CDIM; ++k) {
    float xv = row[k];
    a1 = __fadd_rn(a1, __fmul_rn(xv, sw[k]));
    a2 = __fadd_rn(a2, __fmul_rn(xv, sw[CDIM + k]));
  }
  p1[n] = a1; p2[n] = a2;
}

// ---------- K1: edge scores + sort keys ----------
__global__ void k_edge_scores(const int* __restrict__ ei, const float* __restrict__ p1,
                              const float* __restrict__ p2, const float* __restrict__ lb,
                              float* __restrict__ e, unsigned* __restrict__ keyA,
                              int* __restrict__ payA) {
  int i = blockIdx.x * blockDim.x + threadIdx.x;
  if (i >= N_EDGES) return;
  int s = ei[i], d = ei[N_EDGES + i];
  float z = __fadd_rn(__fadd_rn(p1[s], p2[d]), lb[0]);
  float ev = __fadd_rn(xla_tanh(z), 0.5f);
  e[i] = ev;
  unsigned u = __float_as_uint(ev);
  u = (u >> 31) ? ~u : (u | 0x80000000u);   // ascending-order bits of e
  keyA[i] = ~u;                              // ascending key == descending e; ties stable by idx
  payA[i] = i;
}

// ---------- radix sort (stable LSD, 4x8 bits) ----------
__global__ void k_radix_hist(const unsigned* __restrict__ key, int n, int shift,
                             unsigned* __restrict__ hist) {
  __shared__ unsigned h[256];
  int t = threadIdx.x;
  h[t] = 0;
  __syncthreads();
  int base = blockIdx.x * BE;
  for (int j = t; j < BE; j += 256) {
    int idx = base + j;
    if (idx < n) atomicAdd(&h[(key[idx] >> shift) & 255u], 1u);
  }
  __syncthreads();
  hist[t * NBLK + blockIdx.x] = h[t];
}

__global__ void k_radix_scan(unsigned* __restrict__ hist) {
  __shared__ unsigned sums[256];
  int t = threadIdx.x;
  unsigned rs = 0;
  for (int b = 0; b < NBLK; ++b) rs += hist[t * NBLK + b];
  sums[t] = rs;
  __syncthreads();
  for (int off = 1; off < 256; off <<= 1) {
    unsigned u2 = (t >= off) ? sums[t - off] : 0u;
    __syncthreads();
    sums[t] += u2;
    __syncthreads();
  }
  unsigned run = sums[t] - rs;   // exclusive base for bin t
  for (int b = 0; b < NBLK; ++b) {
    unsigned tmp = hist[t * NBLK + b];
    hist[t * NBLK + b] = run;
    run += tmp;
  }
}

__global__ void k_radix_scatter(const unsigned* __restrict__ key, const int* __restrict__ pay,
                                int n, int shift, const unsigned* __restrict__ hist,
                                unsigned* __restrict__ keyo, int* __restrict__ payo) {
  __shared__ unsigned mask[256][8];
  __shared__ unsigned rbase[256];
  int t = threadIdx.x;
  rbase[t] = hist[t * NBLK + blockIdx.x];
  __syncthreads();
  int base = blockIdx.x * BE;
  for (int tile = 0; tile < BE / 256; ++tile) {
    for (int wq = 0; wq < 8; ++wq) mask[t][wq] = 0u;
    __syncthreads();
    int idx = base + tile * 256 + t;
    unsigned k = 0; int bin = 0; int valid = (idx < n);
    if (valid) {
      k = key[idx];
      bin = (k >> shift) & 255;
      atomicOr(&mask[bin][t >> 5], 1u << (t & 31));
    }
    __syncthreads();
    if (valid) {
      int w = t >> 5;
      unsigned r = 0;
      for (int w2 = 0; w2 < w; ++w2) r += __popc(mask[bin][w2]);
      r += __popc(mask[bin][w] & ((1u << (t & 31)) - 1u));
      unsigned pos = rbase[bin] + r;
      keyo[pos] = k;
      payo[pos] = pay[idx];
    }
    __syncthreads();
    unsigned c = 0;
    for (int wq = 0; wq < 8; ++wq) c += __popc(mask[t][wq]);
    rbase[t] += c;
    __syncthreads();
  }
}

// ---------- K14: gather sorted endpoints + packed worklist + zero take ----------
// packed entry: (p << 30) | (s << 15) | d   with p = sorted position (= priority)
__global__ void k_gather_sorted(const int* __restrict__ pay, const int* __restrict__ ei,
                                int* __restrict__ ss, int* __restrict__ dd,
                                unsigned long long* __restrict__ wl,
                                unsigned char* __restrict__ take) {
  int i = blockIdx.x * blockDim.x + threadIdx.x;
  if (i >= N_EDGES) return;
  int o = pay[i];
  int s = ei[o];
  int d = ei[N_EDGES + o];
  ss[i] = s;
  dd[i] = d;
  wl[i] = ((unsigned long long)i << 30) | ((unsigned long long)(unsigned)s << 15)
        | (unsigned long long)(unsigned)d;
  take[i] = 0;
}

// ---------- K16: persistent single-block EXACT sequential greedy matching ----------
// Chunked over the sorted edge list (8192/chunk). Per chunk:
//  1) 16 waves stage + alive-check (avail both endpoints) and ORDER-PRESERVING
//     compact alive edges into LDS (dead edges never revive -> safe to drop).
//  2) 16 waves build per-edge intra-group KILL-MASKS (bit j>i set if edge j
//     shares an endpoint with edge i; self bit included).
//  3) Wave 0 walks alive groups in order: recheck avail (cross-group kills
//     within the chunk), ballot -> am. Each lane holds ITS OWN kill-mask in
//     registers; the serial loop state (am,tk,j) is wave-uniform, so the
//     per-take fetch is v_readlane (~5-10cy VALU) instead of a dependent
//     ~120cy LDS read:  j=ffs(am); tk|=1<<j; am&=~readlane(km,j).
//     Taken lanes then clear avail and set take[] in parallel.
// Take-set == sequential greedy (order preserved; all earlier-edge conflicts
// covered by compaction-drop + recheck + kill-masks) -> outputs bit-identical.
__global__ __launch_bounds__(1024) void k_match(const unsigned long long* __restrict__ wl,
                                                unsigned char* __restrict__ take,
                                                int* __restrict__ g_avail) {
  __shared__ unsigned char avail[N_NODES];          // 20000 B
  __shared__ unsigned long long comp[CH];           // 65536 B
  __shared__ unsigned long long kmask[CH];          // 65536 B
  __shared__ unsigned gcnt[NGRP];                   // 512 B
  __shared__ unsigned gbase[NGRP];                  // 512 B
  __shared__ int s_ncomp;
  int t = threadIdx.x;
  int lane = t & 63, wid = t >> 6;
  unsigned long long lmask_lt = (lane == 0) ? 0ull : (~0ull >> (64 - lane));
  for (int n = t; n < N_NODES; n += 1024) avail[n] = 1;
  __syncthreads();
  for (int c = 0; c < NCH; ++c) {
    int base = c * CH;
    // --- 1a) stage + alive-count (wave wid owns raw groups wid*8 .. wid*8+7)
    unsigned long long myv[8];
    unsigned char myal[8];
    for (int it = 0; it < 8; ++it) {
      int rg = wid * 8 + it;
      int i = base + rg * 64 + lane;
      unsigned long long v = (i < N_EDGES) ? wl[i] : 0ull;
      bool a = false;
      if (i < N_EDGES) {
        int d = (int)(v & 0x7FFFu);
        int s = (int)((v >> 15) & 0x7FFFu);
        a = avail[s] && avail[d];
      }
      myv[it] = v; myal[it] = a ? 1 : 0;
      unsigned long long bal = __ballot(a);
      if (lane == 0) gcnt[rg] = (unsigned)__popcll(bal);
    }
    __syncthreads();
    // --- 1b) exclusive scan of 128 raw-group counts (wave 0)
    if (wid == 0) {
      unsigned a0 = gcnt[lane], a1 = gcnt[64 + lane];
      unsigned s0 = a0;
      for (int o = 1; o < 64; o <<= 1) { unsigned u = __shfl_up(s0, o); if (lane >= o) s0 += u; }
      unsigned tot0 = __shfl(s0, 63);
      unsigned s1 = a1;
      for (int o = 1; o < 64; o <<= 1) { unsigned u = __shfl_up(s1, o); if (lane >= o) s1 += u; }
      gbase[lane] = s0 - a0;
      gbase[64 + lane] = tot0 + s1 - a1;
      if (lane == 63) s_ncomp = (int)(tot0 + s1);
    }
    __syncthreads();
    // --- 1c) order-preserving writeback of alive edges
    for (int it = 0; it < 8; ++it) {
      int rg = wid * 8 + it;
      unsigned long long bal = __ballot(myal[it] != 0);
      if (myal[it]) {
        unsigned r = (unsigned)__popcll(bal & lmask_lt);
        comp[gbase[rg] + r] = myv[it];
      }
    }
    __syncthreads();
    int ncomp = s_ncomp;
    // --- 2) kill-mask build over compacted groups (16 waves round-robin)
    for (int g = wid; g * 64 < ncomp; g += 16) {
      int i = g * 64 + lane;
      unsigned long long v = (i < ncomp) ? comp[i] : 0ull;
      int d = (int)(v & 0x7FFFu);
      int s = (int)((v >> 15) & 0x7FFFu);
      unsigned long long km = 1ull << lane;   // self bit
      if (i < ncomp) {
        int glen = ncomp - g * 64; if (glen > 64) glen = 64;
        for (int j = lane + 1; j < glen; ++j) {
          unsigned long long vj = comp[g * 64 + j];
          int dj = (int)(vj & 0x7FFFu);
          int sj = (int)((vj >> 15) & 0x7FFFu);
          if (sj == s || sj == d || dj == s || dj == d) km |= 1ull << j;
        }
      }
      kmask[g * 64 + lane] = km;
    }
    __syncthreads();
    // --- 3) wave-0 exact serial walk (readlane-based take loop)
    if (wid == 0) {
      for (int g = 0; g * 64 < ncomp; ++g) {
        int i = g * 64 + lane;
        unsigned long long v = (i < ncomp) ? comp[i] : 0ull;
        int d = (int)(v & 0x7FFFu);
        int s = (int)((v >> 15) & 0x7FFFu);
        unsigned long long km = (i < ncomp) ? kmask[i] : 0ull;
        unsigned km_lo = (unsigned)km;
        unsigned km_hi = (unsigned)(km >> 32);
        bool alive = (i < ncomp) && avail[s] && avail[d];
        unsigned long long am = __ballot(alive);
        unsigned long long tk = 0;
        while (am) {
          int j = __ffsll((long long)am) - 1;
          tk |= 1ull << j;
          unsigned long long kj =
              ((unsigned long long)(unsigned)__builtin_amdgcn_readlane((int)km_hi, j) << 32)
            | (unsigned long long)(unsigned)__builtin_amdgcn_readlane((int)km_lo, j);
          am &= ~kj;   // kills j itself + later same-endpoint edges in group
        }
        if ((tk >> lane) & 1ull) {
          take[(unsigned)(v >> 30)] = 1;
          avail[s] = 0; avail[d] = 0;
        }
      }
    }
    __syncthreads();
  }
  for (int n = t; n < N_NODES; n += 1024) g_avail[n] = avail[n];
}

// ---------- K17/K17b: partial sums ----------
__global__ void k_take_part(const unsigned char* __restrict__ take, unsigned* __restrict__ tpart) {
  __shared__ unsigned s[256];
  int t = threadIdx.x; int base = blockIdx.x * BE;
  unsigned c = 0;
  for (int j = t; j < BE; j += 256) { int idx = base + j; if (idx < N_EDGES) c += take[idx]; }
  s[t] = c; __syncthreads();
  for (int off = 128; off > 0; off >>= 1) { if (t < off) s[t] += s[t + off]; __syncthreads(); }
  if (t == 0) tpart[blockIdx.x] = s[0];
}

__global__ void k_avail_part(const int* __restrict__ g_avail, unsigned* __restrict__ apart) {
  __shared__ unsigned s[256];
  int t = threadIdx.x; int base = blockIdx.x * BE;
  unsigned c = 0;
  for (int j = t; j < BE; j += 256) { int idx = base + j; if (idx < N_NODES) c += (unsigned)g_avail[idx]; }
  s[t] = c; __syncthreads();
  for (int off = 128; off > 0; off >>= 1) { if (t < off) s[t] += s[t + off]; __syncthreads(); }
  if (t == 0) apart[blockIdx.x] = s[0];
}

// ---------- K18: scan partials, compute n_matched / num_clusters ----------
__global__ void k_scan_parts(unsigned* __restrict__ tpart, unsigned* __restrict__ apart,
                             int* __restrict__ scal) {
  __shared__ unsigned arr[512];
  int t = threadIdx.x;   // 512 threads
  unsigned v = (t < NBLK) ? tpart[t] : 0u;
  arr[t] = v;
  __syncthreads();
  for (int off = 1; off < 512; off <<= 1) {
    unsigned u2 = (t >= off) ? arr[t - off] : 0u;
    __syncthreads();
    arr[t] += u2;
    __syncthreads();
  }
  unsigned excl = arr[t] - v;
  if (t < NBLK) tpart[t] = excl;
  unsigned nm = arr[511];
  __syncthreads();
  if (t == 0) {
    unsigned run = 0;
    for (int b = 0; b < NBN; ++b) { unsigned tmp = apart[b]; apart[b] = run; run += tmp; }
    scal[0] = (int)nm;            // n_matched
    scal[2] = (int)run;           // n singleton
    scal[1] = (int)(nm + run);    // num_clusters
  }
}

// ---------- K19: assign ids to matched clusters ----------
__global__ void k_finalize_taken(const unsigned char* __restrict__ take, const int* __restrict__ pay,
                                 const int* __restrict__ ss, const int* __restrict__ dd,
                                 const float* __restrict__ e, const unsigned* __restrict__ tpart,
                                 int* __restrict__ cluster, int* __restrict__ clu,
                                 int* __restrict__ clv, float* __restrict__ csc) {
  __shared__ unsigned arr[256];
  int t = threadIdx.x; int b = blockIdx.x;
  int base = b * BE + t * 4;
  unsigned char tk[4];
  unsigned c = 0;
  for (int j = 0; j < 4; ++j) {
    int p = base + j;
    tk[j] = (p < N_EDGES) ? take[p] : (unsigned char)0;
    c += tk[j];
  }
  arr[t] = c;
  __syncthreads();
  unsigned v = c;
  for (int off = 1; off < 256; off <<= 1) {
    unsigned u2 = (t >= off) ? arr[t - off] : 0u;
    __syncthreads();
    arr[t] += u2;
    __syncthreads();
  }
  unsigned id = tpart[b] + (arr[t] - v);
  for (int j = 0; j < 4; ++j) {
    int p = base + j;
    if (p < N_EDGES && tk[j]) {
      int s = ss[p], d = dd[p];
      int u = min(s, d), w = max(s, d);
      cluster[s] = (int)id; cluster[d] = (int)id;
      clu[id] = u; clv[id] = w;
      csc[id] = e[pay[p]];
      ++id;
    }
  }
}

// ---------- K19b: singleton clusters ----------
__global__ void k_finalize_single(const int* __restrict__ g_avail, const unsigned* __restrict__ apart,
                                  const int* __restrict__ scal, int* __restrict__ cluster,
                                  int* __restrict__ clu, int* __restrict__ clv,
                                  float* __restrict__ csc) {
  __shared__ unsigned arr[256];
  int t = threadIdx.x; int b = blockIdx.x;
  int base = b * BE + t * 4;
  unsigned char av[4];
  unsigned c = 0;
  for (int j = 0; j < 4; ++j) {
    int n = base + j;
    av[j] = (n < N_NODES) ? (unsigned char)g_avail[n] : (unsigned char)0;
    c += av[j];
  }
  arr[t] = c;
  __syncthreads();
  unsigned v = c;
  for (int off = 1; off < 256; off <<= 1) {
    unsigned u2 = (t >= off) ? arr[t - off] : 0u;
    __syncthreads();
    arr[t] += u2;
    __syncthreads();
  }
  unsigned id = (unsigned)scal[0] + apart[b] + (arr[t] - v);
  for (int j = 0; j < 4; ++j) {
    int n = base + j;
    if (n < N_NODES && av[j]) {
      cluster[n] = (int)id;
      clu[id] = n; clv[id] = n;
      csc[id] = 1.0f;
      ++id;
    }
  }
}

// ---------- outputs ----------
__global__ void k_out_x(const float* __restrict__ x, const int* __restrict__ clu,
                        const int* __restrict__ clv, const float* __restrict__ csc,
                        const int* __restrict__ scal, float* __restrict__ out) {
  int c = blockIdx.x; int t = threadIdx.x;
  int nc = scal[1];
  float v = 0.f;
  if (c < nc) {
    int u = clu[c], w = clv[c];
    float a = x[(size_t)u * CDIM + t];
    if (w != u) a = __fadd_rn(a, x[(size_t)w * CDIM + t]);
    v = __fmul_rn(a, csc[c]);
  }
  out[OFF_X + (size_t)c * CDIM + t] = v;
}

__global__ void k_out_edges(const int* __restrict__ ei, const int* __restrict__ cluster,
                            float* __restrict__ out) {
  int i = blockIdx.x * blockDim.x + threadIdx.x;
  if (i < 2 * N_EDGES) out[OFF_EI + i] = (float)cluster[ei[i]];
}

__global__ void k_out_rest(const int* __restrict__ cluster, const int* __restrict__ clv,
                           const int* __restrict__ batch, const int* __restrict__ scal,
                           float* __restrict__ out) {
  int i = blockIdx.x * blockDim.x + threadIdx.x;
  if (i >= N_NODES) return;
  int nc = scal[1];
  out[OFF_CL + i] = (float)cluster[i];
  out[OFF_B + i] = (i < nc) ? (float)batch[clv[i]] : 0.0f;
  if (i == 0) out[OFF_NC] = (float)nc;
}

extern "C" void kernel_launch(void* const* d_in, const int* in_sizes, int n_in,
                              void* d_out, int out_size, void* d_ws, size_t ws_size,
                              hipStream_t stream) {
  const float* x     = (const float*)d_in[0];
  const int*   ei    = (const int*)d_in[1];
  const int*   batch = (const int*)d_in[2];
  const float* lw    = (const float*)d_in[3];
  const float* lb    = (const float*)d_in[4];
  float* out = (float*)d_out;

  int* w = (int*)d_ws;
  size_t off = 0;
  auto alloc = [&](size_t n) { int* p = w + off; off += n; return p; };
  float*    p1    = (float*)alloc(N_NODES);
  float*    p2    = (float*)alloc(N_NODES);
  float*    e     = (float*)alloc(N_EDGES);
  unsigned* keyA  = (unsigned*)alloc(N_EDGES);
  unsigned* keyB  = (unsigned*)alloc(N_EDGES);
  int*      payA  = (int*)alloc(N_EDGES);
  int*      payB  = (int*)alloc(N_EDGES);
  unsigned* hist  = (unsigned*)alloc(256 * NBLK);
  off = (off + 1) & ~(size_t)1;   // align to 8B for uint64 worklist
  unsigned long long* wl = (unsigned long long*)alloc(2 * N_EDGES);
  unsigned char* take = (unsigned char*)alloc(N_EDGES / 4);
  int*      cluster = (int*)alloc(N_NODES);
  int*      clu   = (int*)alloc(N_NODES);
  int*      clv   = (int*)alloc(N_NODES);
  float*    csc   = (float*)alloc(N_NODES);
  int*      g_avail = (int*)alloc(N_NODES);
  unsigned* tpart = (unsigned*)alloc(NBLK + 1);
  unsigned* apart = (unsigned*)alloc(NBN + 1);
  int*      scal  = (int*)alloc(16);
  // after the sort finishes in (keyA,payA), keyB/payB are dead -> reuse for sorted endpoints
  int* ss = (int*)keyB;
  int* dd = payB;

  // scores
  k_node_dots<<<(N_NODES + 255) / 256, 256, 0, stream>>>(x, lw, p1, p2);
  k_edge_scores<<<(N_EDGES + 255) / 256, 256, 0, stream>>>(ei, p1, p2, lb, e, keyA, payA);

  // stable LSD radix sort, 4 passes: A->B->A->B->A
  for (int pass = 0; pass < 4; ++pass) {
    int shift = pass * 8;
    const unsigned* ki = (pass & 1) ? keyB : keyA;
    unsigned*       ko = (pass & 1) ? keyA : keyB;
    const int*      pi = (pass & 1) ? payB : payA;
    int*            po = (pass & 1) ? payA : payB;
    k_radix_hist<<<NBLK, 256, 0, stream>>>(ki, N_EDGES, shift, hist);
    k_radix_scan<<<1, 256, 0, stream>>>(hist);
    k_radix_scatter<<<NBLK, 256, 0, stream>>>(ki, pi, N_EDGES, shift, hist, ko, po);
  }

  k_gather_sorted<<<(N_EDGES + 255) / 256, 256, 0, stream>>>(payA, ei, ss, dd, wl, take);
  k_match<<<1, 1024, 0, stream>>>(wl, take, g_avail);

  k_take_part<<<NBLK, 256, 0, stream>>>(take, tpart);
  k_avail_part<<<NBN, 256, 0, stream>>>(g_avail, apart);
  k_scan_parts<<<1, 512, 0, stream>>>(tpart, apart, scal);
  k_finalize_taken<<<NBLK, 256, 0, stream>>>(take, payA, ss, dd, e, tpart, cluster, clu, clv, csc);
  k_finalize_single<<<NBN, 256, 0, stream>>>(g_avail, apart, scal, cluster, clu, clv, csc);

  k_out_x<<<N_NODES, CDIM, 0, stream>>>(x, clu, clv, csc, scal, out);
  k_out_edges<<<(2 * N_EDGES + 255) / 256, 256, 0, stream>>>(ei, cluster, out);
  k_out_rest<<<(N_NODES + 255) / 256, 256, 0, stream>>>(cluster, clv, batch, scal, out);
}